// Round 1
// baseline (5716.916 us; speedup 1.0000x reference)
//
#include <hip/hip_runtime.h>

#define B_  256
#define T_  1024
#define H_  64
#define G4  256   // 4*H gates

__device__ __forceinline__ float sigmoidf_(float x) {
    return 1.0f / (1.0f + expf(-x));
}

// One block per batch row (grid=256 -> 1 block/CU), 256 threads = one gate each.
// Gate weights live in registers (64+IN_H fp32 per thread); h/x broadcast via LDS.
template<int IN_H>
__global__ __launch_bounds__(256, 1)
void lstm_layer_kernel(const float* x_in,        // [B,T,IN_H] (may alias h_out)
                       float*       h_out,       // [B,T,H]
                       const float* __restrict__ w_ih,  // [4H, IN_H]
                       const float* __restrict__ w_hh,  // [4H, H]
                       const float* __restrict__ b_ih,  // [4H]
                       const float* __restrict__ b_hh)  // [4H]
{
    const int b   = blockIdx.x;
    const int tid = threadIdx.x;

    __shared__ __align__(16) float h_s[H_];
    __shared__ __align__(16) float x_s[2][(IN_H > 1) ? IN_H : 4];
    __shared__ float gates_s[G4];

    // ---- load this gate's weight rows into registers ----
    float whh_r[H_];
    #pragma unroll
    for (int kk = 0; kk < H_/4; ++kk) {
        float4 v = ((const float4*)(w_hh + (long)tid * H_))[kk];
        whh_r[4*kk+0] = v.x; whh_r[4*kk+1] = v.y;
        whh_r[4*kk+2] = v.z; whh_r[4*kk+3] = v.w;
    }
    float wih_r[IN_H];
    if (IN_H == 1) {
        wih_r[0] = w_ih[tid];
    } else {
        #pragma unroll
        for (int kk = 0; kk < IN_H/4; ++kk) {
            float4 v = ((const float4*)(w_ih + (long)tid * IN_H))[kk];
            wih_r[4*kk+0] = v.x; wih_r[4*kk+1] = v.y;
            wih_r[4*kk+2] = v.z; wih_r[4*kk+3] = v.w;
        }
    }
    const float bias = b_ih[tid] + b_hh[tid];

    float c = 0.f;                       // cell state, meaningful for tid < 64
    if (tid < H_) h_s[tid] = 0.f;
    if (IN_H > 1) {
        if (tid < H_) x_s[0][tid] = x_in[((long)b * T_ + 0) * IN_H + tid];
    }
    __syncthreads();

    float x0 = 0.f;                      // layer-0 scalar input for current step
    if (IN_H == 1) x0 = x_in[(long)b * T_ + 0];

    int cur = 0;
    for (int t = 0; t < T_; ++t) {
        // ---- prefetch next step's input (latency hidden by gate matmul) ----
        float xn = 0.f;
        if (IN_H == 1) {
            if (t + 1 < T_) xn = x_in[(long)b * T_ + t + 1];
        } else {
            if (tid < H_ && t + 1 < T_)
                xn = x_in[((long)b * T_ + (t + 1)) * IN_H + tid];
        }

        // ---- gate 'tid': dot(wih, x) + dot(whh, h) + bias ----
        float a0 = bias, a1 = 0.f, a2 = 0.f, a3 = 0.f;
        if (IN_H == 1) {
            a0 += wih_r[0] * x0;
        } else {
            const float4* x4 = (const float4*)&x_s[cur][0];
            #pragma unroll
            for (int kk = 0; kk < IN_H/4; ++kk) {
                float4 v = x4[kk];
                a0 += wih_r[4*kk+0] * v.x; a1 += wih_r[4*kk+1] * v.y;
                a2 += wih_r[4*kk+2] * v.z; a3 += wih_r[4*kk+3] * v.w;
            }
        }
        {
            const float4* h4 = (const float4*)h_s;
            #pragma unroll
            for (int kk = 0; kk < H_/4; ++kk) {
                float4 v = h4[kk];
                a0 += whh_r[4*kk+0] * v.x; a1 += whh_r[4*kk+1] * v.y;
                a2 += whh_r[4*kk+2] * v.z; a3 += whh_r[4*kk+3] * v.w;
            }
        }
        gates_s[tid] = (a0 + a1) + (a2 + a3);
        __syncthreads();

        // ---- cell update on wave 0 (PyTorch gate order i,f,g,o) ----
        if (tid < H_) {
            float gi = gates_s[tid];
            float gf = gates_s[H_   + tid];
            float gg = gates_s[2*H_ + tid];
            float go = gates_s[3*H_ + tid];
            float i_ = sigmoidf_(gi);
            float f_ = sigmoidf_(gf);
            float g_ = tanhf(gg);
            float o_ = sigmoidf_(go);
            c = f_ * c + i_ * g_;
            float h = o_ * tanhf(c);
            h_s[tid] = h;
            h_out[((long)b * T_ + t) * H_ + tid] = h;
            if (IN_H > 1) x_s[cur ^ 1][tid] = xn;
        }
        __syncthreads();
        if (IN_H == 1) x0 = xn;
        cur ^= 1;
    }
}

// out[r] = W2 @ relu(W1 @ relu(h_r) + b1) + b2, one thread per (b,t) row.
__global__ __launch_bounds__(256, 1)
void mlp_head_kernel(const float* __restrict__ hbuf,  // [B*T, H]
                     const float* __restrict__ W1,    // [H, H]
                     const float* __restrict__ b1,    // [H]
                     const float* __restrict__ W2,    // [1, H]
                     const float* __restrict__ b2,    // [1]
                     float* __restrict__ out)         // [B*T]
{
    __shared__ __align__(16) float W1_s[H_ * H_];
    __shared__ float b1_s[H_];
    __shared__ float W2_s[H_];
    const int tid = threadIdx.x;

    #pragma unroll
    for (int i = 0; i < (H_ * H_ / 4) / 256; ++i)   // 1024 float4 / 256 threads
        ((float4*)W1_s)[i * 256 + tid] = ((const float4*)W1)[i * 256 + tid];
    if (tid < H_) { b1_s[tid] = b1[tid]; W2_s[tid] = W2[tid]; }
    __syncthreads();
    const float b2v = b2[0];

    const long r = (long)blockIdx.x * 256 + tid;
    if (r >= (long)B_ * T_) return;

    float4 row4[16];
    const float4* src = (const float4*)(hbuf + r * H_);
    #pragma unroll
    for (int kk = 0; kk < 16; ++kk) {
        float4 v = src[kk];
        row4[kk] = make_float4(fmaxf(v.x, 0.f), fmaxf(v.y, 0.f),
                               fmaxf(v.z, 0.f), fmaxf(v.w, 0.f));
    }

    float acc = 0.f;
    for (int j = 0; j < H_; ++j) {
        const float4* w4 = (const float4*)&W1_s[j * H_];
        float a0 = 0.f, a1 = 0.f, a2 = 0.f, a3 = 0.f;
        #pragma unroll
        for (int kk = 0; kk < 16; ++kk) {
            float4 w = w4[kk];
            a0 += row4[kk].x * w.x; a1 += row4[kk].y * w.y;
            a2 += row4[kk].z * w.z; a3 += row4[kk].w * w.w;
        }
        float y = b1_s[j] + (a0 + a1) + (a2 + a3);
        y = fmaxf(y, 0.f);
        acc += y * W2_s[j];
    }
    out[r] = acc + b2v;
}

extern "C" void kernel_launch(void* const* d_in, const int* in_sizes, int n_in,
                              void* d_out, int out_size, void* d_ws, size_t ws_size,
                              hipStream_t stream) {
    const float* x     = (const float*)d_in[0];   // [B,T,1]
    const float* w_ih0 = (const float*)d_in[1];   // [4H,1]
    const float* w_ihr = (const float*)d_in[2];   // [L-1,4H,H]
    const float* w_hh  = (const float*)d_in[3];   // [L,4H,H]
    const float* b_ih  = (const float*)d_in[4];   // [L,4H]
    const float* b_hh  = (const float*)d_in[5];   // [L,4H]
    const float* W1    = (const float*)d_in[6];   // [H,H]
    const float* b1    = (const float*)d_in[7];   // [H]
    const float* W2    = (const float*)d_in[8];   // [1,H]
    const float* b2    = (const float*)d_in[9];   // [1]
    // d_in[10] = future (0) — single pass.

    float* out = (float*)d_out;
    float* buf = (float*)d_ws;                    // [B,T,H] fp32 = 64 MB, reused in-place

    dim3 block(256);

    // layer 0 (input_size = 1)
    lstm_layer_kernel<1><<<dim3(B_), block, 0, stream>>>(
        x, buf, w_ih0, w_hh, b_ih, b_hh);

    // layers 1..4 (input_size = 64), in-place on buf
    for (int l = 1; l < 5; ++l) {
        lstm_layer_kernel<64><<<dim3(B_), block, 0, stream>>>(
            buf, buf,
            w_ihr + (long)(l - 1) * G4 * H_,
            w_hh  + (long)l * G4 * H_,
            b_ih  + (long)l * G4,
            b_hh  + (long)l * G4);
    }

    // MLP head: relu -> [64x64]+relu -> [1x64]
    mlp_head_kernel<<<dim3((B_ * T_) / 256), block, 0, stream>>>(
        buf, W1, b1, W2, b2, out);
}